// Round 3
// baseline (872.163 us; speedup 1.0000x reference)
//
#include <hip/hip_runtime.h>
#include <hip/hip_bf16.h>

#define C_   256
#define P_   1024
#define N_   32768
#define K_   8192
#define QOFF 8388608   // float offset of indices in d_out
#define CAP  88
#define EPS  8e-4f
#define KSPLIT 2
#define KCHUNK (K_ / KSPLIT)   // 4096

// scratch layout inside d_out's quantized region (byte offsets). Everything is
// consumed before gather overwrites [0, 32MB).
#define XBF_OFF   0u          // ushort[32768*256]  16MB   bf16(x) [n][c]
#define CBBF_OFF  16777216u   // ushort[8192*256]    4MB   bf16(cb) [k][c]
#define CAND_OFF  20971520u   // int[32768*88]    11.0MB   candidate lists
#define CNT_OFF   32505856u   // int[32768]
#define XSQ_OFF   32636928u   // float[32768]
#define CBSQ_OFF  32768000u   // float[8192]   (ends 32,800,768 < 33,554,432)

typedef __attribute__((ext_vector_type(8))) short bf16x8;
typedef __attribute__((ext_vector_type(4))) float f32x4;

__device__ inline void gload_lds16(const void* g, void* l) {
    __builtin_amdgcn_global_load_lds((const __attribute__((address_space(1))) void*)g,
                                     (__attribute__((address_space(3))) void*)l, 16, 0, 0);
}
__device__ inline unsigned short bfbits(float f) {
    __hip_bfloat16 h = __float2bfloat16(f);
    return *(unsigned short*)&h;
}

// ---------- prep_x: transpose x -> bf16 [n][c], xsq[n] (f64 sum of f32 squares), cnt=0 ----------
__global__ __launch_bounds__(256) void prep_x(const float* __restrict__ x,
                                              char* __restrict__ outb) {
    __shared__ float xs[C_][66];
    unsigned short* xbf = (unsigned short*)(outb + XBF_OFF);
    float* xsq = (float*)(outb + XSQ_OFF);
    int*   cnt = (int*)(outb + CNT_OFF);
    const int t = threadIdx.x;
    const int n0 = blockIdx.x * 64;
    const int b = n0 >> 10, p0 = n0 & 1023;
    for (int i = 0; i < 64; ++i) {
        int f = t + 256 * i; int c = f >> 6, nl = f & 63;
        xs[c][nl] = x[(b * C_ + c) * P_ + p0 + nl];
    }
    __syncthreads();
    if (t < 64) {
        double acc = 0.0;
        for (int c = 0; c < C_; ++c) { float v = xs[c][t]; float pq = v * v; acc += (double)pq; }
        xsq[n0 + t] = (float)acc;
        cnt[n0 + t] = 0;
    }
    for (int i = 0; i < 64; ++i) {
        int f = t + 256 * i; int nl = f >> 8, c = f & 255;
        xbf[(n0 + nl) * C_ + c] = bfbits(xs[c][nl]);
    }
}

// ---------- prep_cb: cbsq (f32 squares, f64 sum, round once) + bf16 copy ----------
__global__ __launch_bounds__(256) void prep_cb(const float* __restrict__ cb,
                                               char* __restrict__ outb) {
    float* cbsq = (float*)(outb + CBSQ_OFF);
    unsigned short* cbbf = (unsigned short*)(outb + CBBF_OFF);
    const int row  = blockIdx.x * 4 + (threadIdx.x >> 6);
    const int lane = threadIdx.x & 63;
    const float4 v = *reinterpret_cast<const float4*>(cb + row * C_ + lane * 4);
    float p0 = v.x * v.x, p1 = v.y * v.y, p2 = v.z * v.z, p3 = v.w * v.w;
    double acc = (double)p0 + (double)p1 + (double)p2 + (double)p3;
    for (int off = 32; off; off >>= 1) acc += __shfl_down(acc, off, 64);
    if (lane == 0) cbsq[row] = (float)acc;
    ushort4 u = { bfbits(v.x), bfbits(v.y), bfbits(v.z), bfbits(v.w) };
    *reinterpret_cast<ushort4*>(cbbf + row * C_ + lane * 4) = u;
}

// ---------- vq_online: MFMA screen with per-block online threshold ----------
// grid (N/128, KSPLIT). Block: 256 thr, 2x2 waves over (n,k). Per k-panel (128 k):
//   4 c-chunks of 64: swizzled global_load_lds stage + 16x16x32 MFMA.
// Then: per-row min -> running min (LDS) -> collect scores < min+EPS.
__global__ __launch_bounds__(256) void vq_online(char* __restrict__ outb) {
    __shared__ unsigned short tA[128 * 64];   // 16KB, XOR-swizzled granules
    __shared__ unsigned short tB[128 * 64];   // 16KB
    __shared__ float csq_l[KCHUNK];           // 16KB
    __shared__ float thbuf[128];
    __shared__ float wmin[2][128];
    const unsigned short* xbf  = (const unsigned short*)(outb + XBF_OFF);
    const unsigned short* cbbf = (const unsigned short*)(outb + CBBF_OFF);
    const float* cbsq = (const float*)(outb + CBSQ_OFF);
    int* cnt  = (int*)(outb + CNT_OFF);
    int* cand = (int*)(outb + CAND_OFF);

    const int t = threadIdx.x;
    const int l = t & 63, w = t >> 6;
    const int wn = w >> 1, wk = w & 1;
    const int n0 = blockIdx.x * 128;
    const int chunk0 = blockIdx.y * KCHUNK;

    // stage this chunk's cbsq into LDS (linear; reads are conflict-free)
    #pragma unroll
    for (int i = 0; i < 4; ++i)
        gload_lds16(cbsq + chunk0 + i * 1024 + w * 256 + l * 4,
                    (char*)csq_l + i * 4096 + w * 1024);
    if (t < 128) thbuf[t] = 3.0e38f;

    const int lr3 = l >> 3;                       // staging row-within-8
    const int lg  = ((l & 7) ^ (lr3 & 7)) * 8;    // swizzled source granule (ushorts)

    for (int p = 0; p < KCHUNK / 128; ++p) {
        const int k0 = chunk0 + p * 128;

        f32x4 acc[4][4];
        #pragma unroll
        for (int i = 0; i < 4; ++i)
            #pragma unroll
            for (int j = 0; j < 4; ++j) acc[i][j] = (f32x4)(0.f);

        for (int ct = 0; ct < 4; ++ct) {
            const int c0 = ct * 64;
            #pragma unroll
            for (int s = 0; s < 4; ++s) {
                const int row = w * 8 + s * 32 + lr3;
                gload_lds16(xbf  + (unsigned)(n0 + row) * C_ + c0 + lg, (char*)tA + w * 1024 + s * 4096);
                gload_lds16(cbbf + (unsigned)(k0 + row) * C_ + c0 + lg, (char*)tB + w * 1024 + s * 4096);
            }
            __syncthreads();       // drains vmcnt: tiles ready
            #pragma unroll
            for (int cs = 0; cs < 2; ++cs) {
                const int gb = (((cs * 4) + (l >> 4)) ^ (l & 7)) * 16;  // swizzled read (row&7 == l&7)
                bf16x8 a[4], bb[4];
                #pragma unroll
                for (int i = 0; i < 4; ++i) {
                    a[i]  = *reinterpret_cast<const bf16x8*>((const char*)tA + (wn * 64 + i * 16 + (l & 15)) * 128 + gb);
                    bb[i] = *reinterpret_cast<const bf16x8*>((const char*)tB + (wk * 64 + i * 16 + (l & 15)) * 128 + gb);
                }
                #pragma unroll
                for (int i = 0; i < 4; ++i)
                    #pragma unroll
                    for (int j = 0; j < 4; ++j)
                        acc[i][j] = __builtin_amdgcn_mfma_f32_16x16x32_bf16(a[i], bb[j], acc[i][j], 0, 0, 0);
            }
            __syncthreads();       // done reading before next stage overwrite
        }

        // ---- epilogue: scores s = cbsq - 2*cross; per-row min over this panel ----
        float cq[4];
        #pragma unroll
        for (int j = 0; j < 4; ++j) cq[j] = csq_l[p * 128 + wk * 64 + j * 16 + (l & 15)];

        float mrow[4][4];
        #pragma unroll
        for (int i = 0; i < 4; ++i)
            #pragma unroll
            for (int q = 0; q < 4; ++q) {
                float m = fmaf(-2.0f, acc[i][0][q], cq[0]);
                #pragma unroll
                for (int j = 1; j < 4; ++j) m = fminf(m, fmaf(-2.0f, acc[i][j][q], cq[j]));
                #pragma unroll
                for (int off = 1; off < 16; off <<= 1) m = fminf(m, __shfl_xor(m, off, 64));
                mrow[i][q] = m;
            }
        if ((l & 15) == 0) {
            #pragma unroll
            for (int i = 0; i < 4; ++i)
                #pragma unroll
                for (int q = 0; q < 4; ++q)
                    wmin[wk][wn * 64 + i * 16 + (l >> 4) * 4 + q] = mrow[i][q];
        }
        __syncthreads();
        if (t < 128) thbuf[t] = fminf(thbuf[t], fminf(wmin[0][t], wmin[1][t]));
        __syncthreads();

        // ---- collect: s < running_min + EPS (includes this panel's min) ----
        #pragma unroll
        for (int i = 0; i < 4; ++i) {
            float th[4];
            #pragma unroll
            for (int q = 0; q < 4; ++q) th[q] = thbuf[wn * 64 + i * 16 + (l >> 4) * 4 + q] + EPS;
            #pragma unroll
            for (int j = 0; j < 4; ++j) {
                const int kg = k0 + wk * 64 + j * 16 + (l & 15);
                #pragma unroll
                for (int q = 0; q < 4; ++q) {
                    const float s = fmaf(-2.0f, acc[i][j][q], cq[j]);
                    if (s < th[q]) {
                        const int ng = n0 + wn * 64 + i * 16 + (l >> 4) * 4 + q;
                        const int pos = atomicAdd(&cnt[ng], 1);
                        if (pos < CAP) cand[ng * CAP + pos] = kg;
                    }
                }
            }
        }
    }
}

// ---------- rescore: exact f32 chain (round-1 semantics) over candidates ----------
__global__ __launch_bounds__(256) void rescore(const float* __restrict__ x,
                                               const float* __restrict__ cb,
                                               float* __restrict__ outf,
                                               char* __restrict__ outb) {
    __shared__ float xrow[4][C_];
    const float* cbsq = (const float*)(outb + CBSQ_OFF);
    const float* xsq  = (const float*)(outb + XSQ_OFF);
    const int*   cnt  = (const int*)(outb + CNT_OFF);
    const int*   cand = (const int*)(outb + CAND_OFF);
    const int t = threadIdx.x, l = t & 63, w = t >> 6;
    const int n = blockIdx.x * 4 + w;
    const int b = n >> 10, p = n & 1023;
    #pragma unroll
    for (int i = 0; i < 4; ++i) {
        const int c = l + i * 64;
        xrow[w][c] = x[(b * C_ + c) * P_ + p];
    }
    __syncthreads();
    int m = cnt[n]; if (m > CAP) m = CAP;
    float s2 = 3e38f; int bk = 0x7FFFFFFF;
    for (int cidx = l; cidx < m; cidx += 64) {
        const int k = cand[n * CAP + cidx];
        float acc = 0.f;
        const float4* cb4 = reinterpret_cast<const float4*>(cb + k * C_);
        #pragma unroll 4
        for (int c4 = 0; c4 < 64; ++c4) {
            const float4 cv = cb4[c4];
            acc = fmaf(xrow[w][c4 * 4 + 0], cv.x, acc);
            acc = fmaf(xrow[w][c4 * 4 + 1], cv.y, acc);
            acc = fmaf(xrow[w][c4 * 4 + 2], cv.z, acc);
            acc = fmaf(xrow[w][c4 * 4 + 3], cv.w, acc);
        }
        const float s1 = xsq[n] - 2.0f * acc;
        const float sc = s1 + cbsq[k];
        if (sc < s2 || (sc == s2 && k < bk)) { s2 = sc; bk = k; }
    }
    #pragma unroll
    for (int off = 32; off; off >>= 1) {
        const float so = __shfl_xor(s2, off, 64);
        const int   ko = __shfl_xor(bk, off, 64);
        if (so < s2 || (so == s2 && ko < bk)) { s2 = so; bk = ko; }
    }
    if (l == 0) outf[QOFF + n] = (float)bk;
}

// ---------- gather: quantized[b][c][p] = cb[idx[n]][c] ----------
__global__ __launch_bounds__(256) void gather(const float* __restrict__ cb,
                                              float* __restrict__ outf) {
    __shared__ int kf[64];
    const int t = threadIdx.x;
    const int n0 = blockIdx.x * 64;
    const int b = n0 >> 10, p0 = n0 & 1023;
    if (t < 64) kf[t] = (int)outf[QOFF + n0 + t];
    __syncthreads();
    for (int i = 0; i < 64; ++i) {
        int f = t + 256 * i; int c = f >> 6, nl = f & 63;
        outf[(b * C_ + c) * P_ + p0 + nl] = cb[kf[nl] * C_ + c];
    }
}

extern "C" void kernel_launch(void* const* d_in, const int* in_sizes, int n_in,
                              void* d_out, int out_size, void* d_ws, size_t ws_size,
                              hipStream_t stream) {
    const float* x  = (const float*)d_in[0];
    const float* cb = (const float*)d_in[1];
    float* outf = (float*)d_out;
    char*  outb = (char*)d_out;

    prep_x<<<N_ / 64, 256, 0, stream>>>(x, outb);
    prep_cb<<<K_ / 4, 256, 0, stream>>>(cb, outb);
    vq_online<<<dim3(N_ / 128, KSPLIT), 256, 0, stream>>>(outb);
    rescore<<<N_ / 4, 256, 0, stream>>>(x, cb, outf, outb);
    gather<<<N_ / 64, 256, 0, stream>>>(cb, outf);
}

// Round 5
// 730.662 us; speedup vs baseline: 1.1937x; 1.1937x over previous
//
#include <hip/hip_runtime.h>
#include <hip/hip_bf16.h>

#define C_   256
#define P_   1024
#define N_   32768
#define K_   8192
#define QOFF 8388608   // float offset of indices in d_out
#define CAP  88
#define EPS  8e-4f
#define KSPLIT 2
#define KCHUNK (K_ / KSPLIT)     // 4096
#define PANEL  64
#define NPANEL (KCHUNK / PANEL)  // 64

// scratch layout inside d_out's quantized region (byte offsets). Everything is
// consumed before gather overwrites [0, 32MB).
#define XBF_OFF   0u          // ushort[32768*256]  16MB   bf16(x) [n][c]
#define CBBF_OFF  16777216u   // ushort[8192*256]    4MB   bf16(cb) [k][c]
#define CAND_OFF  20971520u   // int[32768*88]    11.0MB   candidate lists
#define CNT_OFF   32505856u   // int[32768]
#define XSQ_OFF   32636928u   // float[32768]
#define CBSQ_OFF  32768000u   // float[8192]   (ends 32,800,768 < 33,554,432)

typedef __attribute__((ext_vector_type(8))) short bf16x8;
typedef __attribute__((ext_vector_type(4))) float f32x4;

__device__ inline void gload_lds16(const void* g, void* l) {
    __builtin_amdgcn_global_load_lds((const __attribute__((address_space(1))) void*)g,
                                     (__attribute__((address_space(3))) void*)l, 16, 0, 0);
}
__device__ inline unsigned short bfbits(float f) {
    __hip_bfloat16 h = __float2bfloat16(f);
    return *(unsigned short*)&h;
}

// ---------- prep_x: transpose x -> bf16 [n][c], xsq[n], cnt=0 ----------
__global__ __launch_bounds__(256) void prep_x(const float* __restrict__ x,
                                              char* __restrict__ outb) {
    __shared__ float xs[C_][66];
    unsigned short* xbf = (unsigned short*)(outb + XBF_OFF);
    float* xsq = (float*)(outb + XSQ_OFF);
    int*   cnt = (int*)(outb + CNT_OFF);
    const int t = threadIdx.x;
    const int n0 = blockIdx.x * 64;
    const int b = n0 >> 10, p0 = n0 & 1023;
    for (int i = 0; i < 64; ++i) {
        int f = t + 256 * i; int c = f >> 6, nl = f & 63;
        xs[c][nl] = x[(b * C_ + c) * P_ + p0 + nl];
    }
    __syncthreads();
    if (t < 64) {
        double acc = 0.0;
        for (int c = 0; c < C_; ++c) { float v = xs[c][t]; float pq = v * v; acc += (double)pq; }
        xsq[n0 + t] = (float)acc;
        cnt[n0 + t] = 0;
    }
    for (int i = 0; i < 64; ++i) {
        int f = t + 256 * i; int nl = f >> 8, c = f & 255;
        xbf[(n0 + nl) * C_ + c] = bfbits(xs[c][nl]);
    }
}

// ---------- prep_cb: cbsq (f32 squares, f64 sum, round once) + bf16 copy ----------
__global__ __launch_bounds__(256) void prep_cb(const float* __restrict__ cb,
                                               char* __restrict__ outb) {
    float* cbsq = (float*)(outb + CBSQ_OFF);
    unsigned short* cbbf = (unsigned short*)(outb + CBBF_OFF);
    const int row  = blockIdx.x * 4 + (threadIdx.x >> 6);
    const int lane = threadIdx.x & 63;
    const float4 v = *reinterpret_cast<const float4*>(cb + row * C_ + lane * 4);
    float p0 = v.x * v.x, p1 = v.y * v.y, p2 = v.z * v.z, p3 = v.w * v.w;
    double acc = (double)p0 + (double)p1 + (double)p2 + (double)p3;
    for (int off = 32; off; off >>= 1) acc += __shfl_down(acc, off, 64);
    if (lane == 0) cbsq[row] = (float)acc;
    ushort4 u = { bfbits(v.x), bfbits(v.y), bfbits(v.z), bfbits(v.w) };
    *reinterpret_cast<ushort4*>(cbbf + row * C_ + lane * 4) = u;
}

// ---------- vq_regs: x-tile in registers, cb panels double-buffered ----------
// grid 512; id&7 -> XCD; XCDs 0-3 own chunk 0, 4-7 chunk 1 (cb chunk 2MB, L2-resident).
// Block: 256 thr, waves (wn,wk) 2x2. Wave holds A-frags for rows wn*64..+63,
// all 256 c (32 bf16x8 = 128 VGPR). Panel = 64 k staged in LDS (XOR-swizzled).
__global__ __launch_bounds__(256, 2) void vq_regs(char* __restrict__ outb) {
    __shared__ unsigned short Bt[2][PANEL * C_];   // 2 x 32KB
    __shared__ float thbuf[128];
    __shared__ float wmin[2][128];
    const unsigned short* xbf  = (const unsigned short*)(outb + XBF_OFF);
    const unsigned short* cbbf = (const unsigned short*)(outb + CBBF_OFF);
    const float* cbsq = (const float*)(outb + CBSQ_OFF);
    int* cnt  = (int*)(outb + CNT_OFF);
    int* cand = (int*)(outb + CAND_OFF);

    const int t = threadIdx.x;
    const int l = t & 63, w = t >> 6;
    const int wn = w >> 1, wk = w & 1;
    const int id = blockIdx.x;
    const int grp = id & 7;
    const int chunkIdx = grp >> 2;                 // XCD 0-3 -> chunk0, 4-7 -> chunk1
    const int nblk = (id >> 3) * 4 + (grp & 3);    // bijective over [0,256)
    const int n0 = nblk * 128;
    const int chunk0 = chunkIdx * KCHUNK;

    // stage a 64-row x 256-c bf16 panel into Bt[buf]; rows linear, granules
    // XOR-swizzled at the SOURCE (gload_lds writes linearly; XOR is involution).
    auto stage64 = [&](const unsigned short* src, int rowbase, int buf) {
        #pragma unroll
        for (int s = 0; s < 8; ++s) {
            const int dr = 2 * (w + 4 * s) + (l >> 5);
            const int gd = l & 31;
            gload_lds16(src + (size_t)(rowbase + dr) * C_ + ((gd ^ (dr & 7)) * 8),
                        (char*)&Bt[buf][0] + (w + 4 * s) * 1024);
        }
    };

    stage64(xbf, n0, 0);
    stage64(xbf, n0 + 64, 1);
    if (t < 128) thbuf[t] = 3.0e38f;
    __syncthreads();                 // x panels staged (drains vmcnt)

    // read A-frags (wave wn reads Bt[wn]); swizzled granule read
    bf16x8 a[4][8];
    #pragma unroll
    for (int i = 0; i < 4; ++i) {
        const int rA = i * 16 + (l & 15);
        #pragma unroll
        for (int kc = 0; kc < 8; ++kc) {
            const int gs = (kc * 4 + (l >> 4)) ^ (rA & 7);
            a[i][kc] = *reinterpret_cast<const bf16x8*>((const char*)&Bt[wn][0] + rA * 512 + gs * 16);
        }
    }
    __syncthreads();                 // a[] reads complete before Bt reuse

    stage64(cbbf, chunk0, 0);        // panel 0

    for (int p = 0; p < NPANEL; ++p) {
        const int cur = p & 1;
        __syncthreads();             // Bt[cur] staged (drains vm); thbuf/wmin quiesced
        if (p + 1 < NPANEL) stage64(cbbf, chunk0 + (p + 1) * PANEL, cur ^ 1);

        // cbsq for this panel's 2 col-tiles (L2-resident; issued early, used late)
        const float cq0 = cbsq[chunk0 + p * 64 + wk * 32 + (l & 15)];
        const float cq1 = cbsq[chunk0 + p * 64 + wk * 32 + 16 + (l & 15)];

        f32x4 acc[4][2];
        #pragma unroll
        for (int i = 0; i < 4; ++i) { acc[i][0] = (f32x4)(0.f); acc[i][1] = (f32x4)(0.f); }

        const int r0 = wk * 32 + (l & 15);
        #pragma unroll
        for (int kc = 0; kc < 8; ++kc) {
            const int gs = (kc * 4 + (l >> 4)) ^ (r0 & 7);   // (r0+16)&7 == r0&7
            const bf16x8 b0 = *reinterpret_cast<const bf16x8*>((const char*)&Bt[cur][0] + r0 * 512 + gs * 16);
            const bf16x8 b1 = *reinterpret_cast<const bf16x8*>((const char*)&Bt[cur][0] + (r0 + 16) * 512 + gs * 16);
            #pragma unroll
            for (int i = 0; i < 4; ++i) {
                acc[i][0] = __builtin_amdgcn_mfma_f32_16x16x32_bf16(a[i][kc], b0, acc[i][0], 0, 0, 0);
                acc[i][1] = __builtin_amdgcn_mfma_f32_16x16x32_bf16(a[i][kc], b1, acc[i][1], 0, 0, 0);
            }
        }

        // scores once into regs; per-row min; rows = wn*64+i*16+(l>>4)*4+q, col = wk*32+j*16+(l&15)
        float sc[4][2][4];
        #pragma unroll
        for (int i = 0; i < 4; ++i)
            #pragma unroll
            for (int q = 0; q < 4; ++q) {
                sc[i][0][q] = fmaf(-2.f, acc[i][0][q], cq0);
                sc[i][1][q] = fmaf(-2.f, acc[i][1][q], cq1);
                float m = fminf(sc[i][0][q], sc[i][1][q]);
                #pragma unroll
                for (int off = 1; off < 16; off <<= 1) m = fminf(m, __shfl_xor(m, off, 64));
                if ((l & 15) == 0) wmin[wk][wn * 64 + i * 16 + (l >> 4) * 4 + q] = m;
            }
        __syncthreads();             // wmin visible

        // collect with th = min(thbuf, wmin0, wmin1) + EPS; merge thbuf in-place
        // (concurrent read/write race is benign: min is idempotent, collect
        //  recomputes the same merged min from wmin directly)
        if (t < 128) thbuf[t] = fminf(thbuf[t], fminf(wmin[0][t], wmin[1][t]));
        #pragma unroll
        for (int i = 0; i < 4; ++i) {
            #pragma unroll
            for (int q = 0; q < 4; ++q) {
                const int rloc = wn * 64 + i * 16 + (l >> 4) * 4 + q;
                const float th = fminf(thbuf[rloc], fminf(wmin[0][rloc], wmin[1][rloc])) + EPS;
                #pragma unroll
                for (int j = 0; j < 2; ++j) {
                    if (sc[i][j][q] < th) {
                        const int ng = n0 + rloc;
                        const int kg = chunk0 + p * 64 + wk * 32 + j * 16 + (l & 15);
                        const int pos = atomicAdd(&cnt[ng], 1);
                        if (pos < CAP) cand[ng * CAP + pos] = kg;
                    }
                }
            }
        }
    }
}

// ---------- rescore: exact f32 chain over candidates; full-scan fallback on overflow ----------
__global__ __launch_bounds__(256) void rescore(const float* __restrict__ x,
                                               const float* __restrict__ cb,
                                               float* __restrict__ outf,
                                               char* __restrict__ outb) {
    __shared__ float xrow[4][C_];
    const float* cbsq = (const float*)(outb + CBSQ_OFF);
    const float* xsq  = (const float*)(outb + XSQ_OFF);
    const int*   cnt  = (const int*)(outb + CNT_OFF);
    const int*   cand = (const int*)(outb + CAND_OFF);
    const int t = threadIdx.x, l = t & 63, w = t >> 6;
    const int n = blockIdx.x * 4 + w;
    const int b = n >> 10, p = n & 1023;
    #pragma unroll
    for (int i = 0; i < 4; ++i) {
        const int c = l + i * 64;
        xrow[w][c] = x[(b * C_ + c) * P_ + p];
    }
    __syncthreads();
    const int m = cnt[n];
    const float xq = xsq[n];
    float s2 = 3e38f; int bk = 0x7FFFFFFF;

    auto score_one = [&](int k) {
        float acc = 0.f;
        const float4* cb4 = reinterpret_cast<const float4*>(cb + k * C_);
        #pragma unroll 4
        for (int c4 = 0; c4 < 64; ++c4) {
            const float4 cv = cb4[c4];
            acc = fmaf(xrow[w][c4 * 4 + 0], cv.x, acc);
            acc = fmaf(xrow[w][c4 * 4 + 1], cv.y, acc);
            acc = fmaf(xrow[w][c4 * 4 + 2], cv.z, acc);
            acc = fmaf(xrow[w][c4 * 4 + 3], cv.w, acc);
        }
        const float s1 = xq - 2.0f * acc;   // exact round-1 f32 chain
        const float sck = s1 + cbsq[k];
        if (sck < s2 || (sck == s2 && k < bk)) { s2 = sck; bk = k; }
    };

    if (m > CAP) {
        // overflow: candidate list incomplete -> exact scan of all K (rare)
        for (int k = l; k < K_; k += 64) score_one(k);
    } else {
        for (int cidx = l; cidx < m; cidx += 64) score_one(cand[n * CAP + cidx]);
    }
    #pragma unroll
    for (int off = 32; off; off >>= 1) {
        const float so = __shfl_xor(s2, off, 64);
        const int   ko = __shfl_xor(bk, off, 64);
        if (so < s2 || (so == s2 && ko < bk)) { s2 = so; bk = ko; }
    }
    if (l == 0) outf[QOFF + n] = (float)bk;
}

// ---------- gather: quantized[b][c][p] = cb[idx[n]][c] ----------
__global__ __launch_bounds__(256) void gather(const float* __restrict__ cb,
                                              float* __restrict__ outf) {
    __shared__ int kf[64];
    const int t = threadIdx.x;
    const int n0 = blockIdx.x * 64;
    const int b = n0 >> 10, p0 = n0 & 1023;
    if (t < 64) kf[t] = (int)outf[QOFF + n0 + t];
    __syncthreads();
    for (int i = 0; i < 64; ++i) {
        int f = t + 256 * i; int c = f >> 6, nl = f & 63;
        outf[(b * C_ + c) * P_ + p0 + nl] = cb[kf[nl] * C_ + c];
    }
}

extern "C" void kernel_launch(void* const* d_in, const int* in_sizes, int n_in,
                              void* d_out, int out_size, void* d_ws, size_t ws_size,
                              hipStream_t stream) {
    const float* x  = (const float*)d_in[0];
    const float* cb = (const float*)d_in[1];
    float* outf = (float*)d_out;
    char*  outb = (char*)d_out;

    prep_x<<<N_ / 64, 256, 0, stream>>>(x, outb);
    prep_cb<<<K_ / 4, 256, 0, stream>>>(cb, outb);
    vq_regs<<<256 * KSPLIT, 256, 0, stream>>>(outb);
    rescore<<<N_ / 4, 256, 0, stream>>>(x, cb, outf, outb);
    gather<<<N_ / 64, 256, 0, stream>>>(cb, outf);
}

// Round 6
// 698.822 us; speedup vs baseline: 1.2480x; 1.0456x over previous
//
#include <hip/hip_runtime.h>
#include <hip/hip_bf16.h>

#define C_   256
#define P_   1024
#define N_   32768
#define K_   8192
#define QOFF 8388608   // float offset of indices in d_out
#define CAP  88
#define EPS  8e-4f
#define KSPLIT 2
#define KCHUNK (K_ / KSPLIT)     // 4096
#define PANEL  64
#define NPANEL (KCHUNK / PANEL)  // 64

// scratch layout inside d_out's quantized region (byte offsets). Everything is
// consumed before gather overwrites [0, 32MB).
#define XBF_OFF   0u          // ushort[32768*256]  16MB   bf16(x) [n][c]
#define CBBF_OFF  16777216u   // ushort[8192*256]    4MB   bf16(cb) [k][c]
#define CAND_OFF  20971520u   // int[32768*88]    11.0MB   candidate lists
#define CNT_OFF   32505856u   // int[32768]
#define XSQ_OFF   32636928u   // float[32768]
#define CBSQ_OFF  32768000u   // float[8192]   (ends 32,800,768 < 33,554,432)

typedef __attribute__((ext_vector_type(8))) short bf16x8;
typedef __attribute__((ext_vector_type(4))) float f32x4;

__device__ inline void gload_lds16(const void* g, void* l) {
    __builtin_amdgcn_global_load_lds((const __attribute__((address_space(1))) void*)g,
                                     (__attribute__((address_space(3))) void*)l, 16, 0, 0);
}
__device__ inline unsigned short bfbits(float f) {
    __hip_bfloat16 h = __float2bfloat16(f);
    return *(unsigned short*)&h;
}

// ---------- prep_x: transpose x -> bf16 [n][c], xsq[n], cnt=0 ----------
__global__ __launch_bounds__(256) void prep_x(const float* __restrict__ x,
                                              char* __restrict__ outb) {
    __shared__ float xs[C_][66];
    unsigned short* xbf = (unsigned short*)(outb + XBF_OFF);
    float* xsq = (float*)(outb + XSQ_OFF);
    int*   cnt = (int*)(outb + CNT_OFF);
    const int t = threadIdx.x;
    const int n0 = blockIdx.x * 64;
    const int b = n0 >> 10, p0 = n0 & 1023;
    for (int i = 0; i < 64; ++i) {
        int f = t + 256 * i; int c = f >> 6, nl = f & 63;
        xs[c][nl] = x[(b * C_ + c) * P_ + p0 + nl];
    }
    __syncthreads();
    if (t < 64) {
        double acc = 0.0;
        for (int c = 0; c < C_; ++c) { float v = xs[c][t]; float pq = v * v; acc += (double)pq; }
        xsq[n0 + t] = (float)acc;
        cnt[n0 + t] = 0;
    }
    for (int i = 0; i < 64; ++i) {
        int f = t + 256 * i; int nl = f >> 8, c = f & 255;
        xbf[(n0 + nl) * C_ + c] = bfbits(xs[c][nl]);
    }
}

// ---------- prep_cb: cbsq (f32 squares, f64 sum, round once) + bf16 copy ----------
__global__ __launch_bounds__(256) void prep_cb(const float* __restrict__ cb,
                                               char* __restrict__ outb) {
    float* cbsq = (float*)(outb + CBSQ_OFF);
    unsigned short* cbbf = (unsigned short*)(outb + CBBF_OFF);
    const int row  = blockIdx.x * 4 + (threadIdx.x >> 6);
    const int lane = threadIdx.x & 63;
    const float4 v = *reinterpret_cast<const float4*>(cb + row * C_ + lane * 4);
    float p0 = v.x * v.x, p1 = v.y * v.y, p2 = v.z * v.z, p3 = v.w * v.w;
    double acc = (double)p0 + (double)p1 + (double)p2 + (double)p3;
    for (int off = 32; off; off >>= 1) acc += __shfl_down(acc, off, 64);
    if (lane == 0) cbsq[row] = (float)acc;
    ushort4 u = { bfbits(v.x), bfbits(v.y), bfbits(v.z), bfbits(v.w) };
    *reinterpret_cast<ushort4*>(cbbf + row * C_ + lane * 4) = u;
}

// ---------- vq_regs: swapped operands (cb=A rows=k, x=B cols=n) ----------
// grid 512; XCDs 0-3 own chunk0, 4-7 chunk1. Block 256 thr, waves (wn,wk) 2x2.
// Wave holds x B-frags for n = wn*64..+63 (128 VGPR). Panel = 64 k in LDS.
// Per-n scores are thread-local over (i,q) -> min = 7 fmin + 2 shfl only.
__global__ __launch_bounds__(256, 2) void vq_regs(char* __restrict__ outb) {
    __shared__ unsigned short Bt[2][PANEL * C_];   // 2 x 32KB
    __shared__ float wmin[2][128];
    const unsigned short* xbf  = (const unsigned short*)(outb + XBF_OFF);
    const unsigned short* cbbf = (const unsigned short*)(outb + CBBF_OFF);
    const float* cbsq = (const float*)(outb + CBSQ_OFF);
    int* cnt  = (int*)(outb + CNT_OFF);
    int* cand = (int*)(outb + CAND_OFF);

    const int t = threadIdx.x;
    const int l = t & 63, w = t >> 6;
    const int wn = w >> 1, wk = w & 1;
    const int id = blockIdx.x;
    const int grp = id & 7;
    const int chunkIdx = grp >> 2;
    const int nblk = (id >> 3) * 4 + (grp & 3);
    const int n0 = nblk * 128;
    const int chunk0 = chunkIdx * KCHUNK;

    auto stage64 = [&](const unsigned short* src, int rowbase, int buf) {
        #pragma unroll
        for (int s = 0; s < 8; ++s) {
            const int dr = 2 * (w + 4 * s) + (l >> 5);
            const int gd = l & 31;
            gload_lds16(src + (size_t)(rowbase + dr) * C_ + ((gd ^ (dr & 7)) * 8),
                        (char*)&Bt[buf][0] + (w + 4 * s) * 1024);
        }
    };

    stage64(xbf, n0, 0);
    stage64(xbf, n0 + 64, 1);
    __syncthreads();                 // x staged (drains vmcnt)

    // x B-frags: bx[j][kc] = X[n = wn*64 + j*16 + (l&15)][kc*32 + (l>>4)*8 ..]
    bf16x8 bx[4][8];
    #pragma unroll
    for (int j = 0; j < 4; ++j) {
        const int rB = j * 16 + (l & 15);
        #pragma unroll
        for (int kc = 0; kc < 8; ++kc) {
            const int gs = (kc * 4 + (l >> 4)) ^ (rB & 7);
            bx[j][kc] = *reinterpret_cast<const bf16x8*>((const char*)&Bt[wn][0] + rB * 512 + gs * 16);
        }
    }
    __syncthreads();                 // bx reads done before Bt reuse

    stage64(cbbf, chunk0, 0);        // panel 0
    float th[4] = {3e38f, 3e38f, 3e38f, 3e38f};

    for (int p = 0; p < NPANEL; ++p) {
        const int cur = p & 1;
        __syncthreads();             // Bt[cur] staged (drains vm)
        if (p + 1 < NPANEL) stage64(cbbf, chunk0 + (p + 1) * PANEL, cur ^ 1);

        // cbsq for this thread's 8 k's (L2-hot, vectorized float4 x2)
        float4 cqv[2];
        #pragma unroll
        for (int i = 0; i < 2; ++i)
            cqv[i] = *reinterpret_cast<const float4*>(cbsq + chunk0 + p * 64 + wk * 32 + i * 16 + (l >> 4) * 4);

        f32x4 acc[4][2];
        #pragma unroll
        for (int j = 0; j < 4; ++j) { acc[j][0] = (f32x4)(0.f); acc[j][1] = (f32x4)(0.f); }

        const int rA = wk * 32 + (l & 15);
        #pragma unroll
        for (int kc = 0; kc < 8; ++kc) {
            const int gs = (kc * 4 + (l >> 4)) ^ (l & 7);
            const bf16x8 ac0 = *reinterpret_cast<const bf16x8*>((const char*)&Bt[cur][0] + rA * 512 + gs * 16);
            const bf16x8 ac1 = *reinterpret_cast<const bf16x8*>((const char*)&Bt[cur][0] + (rA + 16) * 512 + gs * 16);
            #pragma unroll
            for (int j = 0; j < 4; ++j) {
                acc[j][0] = __builtin_amdgcn_mfma_f32_16x16x32_bf16(ac0, bx[j][kc], acc[j][0], 0, 0, 0);
                acc[j][1] = __builtin_amdgcn_mfma_f32_16x16x32_bf16(ac1, bx[j][kc], acc[j][1], 0, 0, 0);
            }
        }

        // scores in place: k = chunk0+p*64+wk*32+i*16+(l>>4)*4+q, n-col = wn*64+j*16+(l&15)
        const float cqa[2][4] = {{cqv[0].x, cqv[0].y, cqv[0].z, cqv[0].w},
                                 {cqv[1].x, cqv[1].y, cqv[1].z, cqv[1].w}};
        #pragma unroll
        for (int j = 0; j < 4; ++j) {
            #pragma unroll
            for (int i = 0; i < 2; ++i)
                #pragma unroll
                for (int q = 0; q < 4; ++q)
                    acc[j][i][q] = fmaf(-2.f, acc[j][i][q], cqa[i][q]);
            float m = fminf(fminf(fminf(acc[j][0][0], acc[j][0][1]), fminf(acc[j][0][2], acc[j][0][3])),
                            fminf(fminf(acc[j][1][0], acc[j][1][1]), fminf(acc[j][1][2], acc[j][1][3])));
            m = fminf(m, __shfl_xor(m, 16, 64));
            m = fminf(m, __shfl_xor(m, 32, 64));
            th[j] = fminf(th[j], m);
        }

        // cross-wave combine at exponential cadence (valid upper bound otherwise)
        if (p < 8 || (p & 7) == 7) {
            if (l < 16) {
                #pragma unroll
                for (int j = 0; j < 4; ++j) wmin[wk][wn * 64 + j * 16 + l] = th[j];
            }
            __syncthreads();
            #pragma unroll
            for (int j = 0; j < 4; ++j)
                th[j] = fminf(th[j], wmin[wk ^ 1][wn * 64 + j * 16 + (l & 15)]);
        }

        // collect
        #pragma unroll
        for (int j = 0; j < 4; ++j) {
            const float thE = th[j] + EPS;
            const int ng = n0 + wn * 64 + j * 16 + (l & 15);
            #pragma unroll
            for (int i = 0; i < 2; ++i)
                #pragma unroll
                for (int q = 0; q < 4; ++q) {
                    if (acc[j][i][q] < thE) {
                        const int kg = chunk0 + p * 64 + wk * 32 + i * 16 + (l >> 4) * 4 + q;
                        const int pos = atomicAdd(&cnt[ng], 1);
                        if (pos < CAP) cand[ng * CAP + pos] = kg;
                    }
                }
        }
    }
}

// ---------- rescore: exact f32 chain; wave-per-candidate, coalesced cb reads ----------
__global__ __launch_bounds__(256) void rescore(const float* __restrict__ x,
                                               const float* __restrict__ cb,
                                               float* __restrict__ outf,
                                               char* __restrict__ outb) {
    __shared__ float xs[C_ * 65];    // xs[c*65 + nl]: bank-clean both ways
    const float* cbsq = (const float*)(outb + CBSQ_OFF);
    const float* xsq  = (const float*)(outb + XSQ_OFF);
    const int*   cnt  = (const int*)(outb + CNT_OFF);
    const int*   cand = (const int*)(outb + CAND_OFF);
    const int t = threadIdx.x, l = t & 63, wv = t >> 6;
    const int nb = blockIdx.x * 64;
    const int b = nb >> 10, p0 = nb & 1023;
    for (int i = 0; i < 64; ++i) {
        int f = t + 256 * i; int c = f >> 6, nl = f & 63;
        xs[c * 65 + nl] = x[(b * C_ + c) * P_ + p0 + nl];
    }
    __syncthreads();

    for (int r = 0; r < 16; ++r) {
        const int row = wv * 16 + r;
        const int n = nb + row;
        const int m = cnt[n];
        const float xq = xsq[n];
        // lane l owns channels {l, l+64, l+128, l+192}
        float xl[4];
        #pragma unroll
        for (int cc = 0; cc < 4; ++cc) xl[cc] = xs[(cc * 64 + l) * 65 + row];

        float s2 = 3e38f; int bk = 0x7FFFFFFF;
        auto score_one = [&](int k) {
            float part = 0.f;
            #pragma unroll
            for (int cc = 0; cc < 4; ++cc)
                part = fmaf(xl[cc], cb[(size_t)k * C_ + cc * 64 + l], part);
            #pragma unroll
            for (int off = 32; off; off >>= 1) part += __shfl_xor(part, off, 64);
            const float s1 = xq - 2.0f * part;   // accurate dot, ref f32 chain
            const float sck = s1 + cbsq[k];
            if (sck < s2 || (sck == s2 && k < bk)) { s2 = sck; bk = k; }
        };

        if (m == 0 || m > CAP) {
            for (int k = 0; k < K_; ++k) score_one(k);      // safe fallback
        } else {
            for (int cidx = 0; cidx < m; ++cidx)
                score_one(__builtin_amdgcn_readfirstlane(cand[n * CAP + cidx]));
        }
        if (l == 0) outf[QOFF + n] = (float)bk;
    }
}

// ---------- gather: quantized[b][c][p] = cb[idx[n]][c] ----------
__global__ __launch_bounds__(256) void gather(const float* __restrict__ cb,
                                              float* __restrict__ outf) {
    __shared__ int kf[64];
    const int t = threadIdx.x;
    const int n0 = blockIdx.x * 64;
    const int b = n0 >> 10, p0 = n0 & 1023;
    if (t < 64) kf[t] = (int)outf[QOFF + n0 + t];
    __syncthreads();
    for (int i = 0; i < 64; ++i) {
        int f = t + 256 * i; int c = f >> 6, nl = f & 63;
        outf[(b * C_ + c) * P_ + p0 + nl] = cb[kf[nl] * C_ + c];
    }
}

extern "C" void kernel_launch(void* const* d_in, const int* in_sizes, int n_in,
                              void* d_out, int out_size, void* d_ws, size_t ws_size,
                              hipStream_t stream) {
    const float* x  = (const float*)d_in[0];
    const float* cb = (const float*)d_in[1];
    float* outf = (float*)d_out;
    char*  outb = (char*)d_out;

    prep_x<<<N_ / 64, 256, 0, stream>>>(x, outb);
    prep_cb<<<K_ / 4, 256, 0, stream>>>(cb, outb);
    vq_regs<<<256 * KSPLIT, 256, 0, stream>>>(outb);
    rescore<<<N_ / 64, 256, 0, stream>>>(x, cb, outf, outb);
    gather<<<N_ / 64, 256, 0, stream>>>(cb, outf);
}